// Round 3
// baseline (1794.435 us; speedup 1.0000x reference)
//
#include <hip/hip_runtime.h>

#define T_TOK 1024
#define D_DIM 2048
#define E_NUM 32
#define F_DIM 768
#define K_TOP 8

typedef __bf16 v8bf __attribute__((ext_vector_type(8)));
typedef float v4f __attribute__((ext_vector_type(4)));
typedef unsigned short v8us __attribute__((ext_vector_type(8)));
typedef unsigned int v4u __attribute__((ext_vector_type(4)));

__device__ __forceinline__ unsigned short f2b(float f) {
  unsigned int u = __builtin_bit_cast(unsigned int, f);
  u += 0x7fffu + ((u >> 16) & 1u);   // RNE
  return (unsigned short)(u >> 16);
}
__device__ __forceinline__ float b2f(unsigned short s) {
  return __builtin_bit_cast(float, (unsigned int)s << 16);
}
__device__ __forceinline__ v8bf cvt8(v4f a, v4f b) {
  v8bf r;
  r[0] = (__bf16)a[0]; r[1] = (__bf16)a[1]; r[2] = (__bf16)a[2]; r[3] = (__bf16)a[3];
  r[4] = (__bf16)b[0]; r[5] = (__bf16)b[1]; r[6] = (__bf16)b[2]; r[7] = (__bf16)b[3];
  return r;
}

// ---------------- Router: logits (fp32), top-8, bucket, x->bf16 ----------------
__global__ __launch_bounds__(256) void router_kernel(
    const float* __restrict__ x, const float* __restrict__ gw,
    unsigned short* __restrict__ xb, int* __restrict__ counts,
    int* __restrict__ tlist, int* __restrict__ topk_e, int* __restrict__ topk_p,
    float* __restrict__ topk_w, float* __restrict__ wlist)
{
  const int t = blockIdx.x, tid = threadIdx.x;
  const float* xr = x + (size_t)t * D_DIM;

  {  // convert this token's row to bf16
    v4f f0 = *reinterpret_cast<const v4f*>(xr + tid * 8);
    v4f f1 = *reinterpret_cast<const v4f*>(xr + tid * 8 + 4);
    v8us u;
    u[0] = f2b(f0[0]); u[1] = f2b(f0[1]); u[2] = f2b(f0[2]); u[3] = f2b(f0[3]);
    u[4] = f2b(f1[0]); u[5] = f2b(f1[1]); u[6] = f2b(f1[2]); u[7] = f2b(f1[3]);
    *reinterpret_cast<v8us*>(xb + (size_t)t * D_DIM + tid * 8) = u;
  }

  __shared__ float logits[E_NUM];
  const int lane = tid & 63, wave = tid >> 6;
  for (int j = 0; j < 8; ++j) {
    int e = wave * 8 + j;
    const float* wr = gw + (size_t)e * D_DIM;
    float s = 0.f;
#pragma unroll
    for (int i = 0; i < D_DIM / 64; ++i) s = fmaf(xr[lane + i * 64], wr[lane + i * 64], s);
#pragma unroll
    for (int off = 32; off > 0; off >>= 1) s += __shfl_xor(s, off);
    if (lane == 0) logits[e] = s;
  }
  __syncthreads();

  if (tid == 0) {
    float lg[E_NUM];
#pragma unroll
    for (int e2 = 0; e2 < E_NUM; ++e2) lg[e2] = logits[e2];
    int sel[K_TOP]; float sv[K_TOP];
    for (int k = 0; k < K_TOP; ++k) {
      int best = 0; float bv = -3.4e38f;
      for (int e2 = 0; e2 < E_NUM; ++e2)
        if (lg[e2] > bv) { bv = lg[e2]; best = e2; }
      sel[k] = best; sv[k] = bv; lg[best] = -3.4e38f;
    }
    float mx = sv[0], s8 = 0.f, ww[K_TOP];
    for (int k = 0; k < K_TOP; ++k) { ww[k] = __expf(sv[k] - mx); s8 += ww[k]; }
    float inv = 1.f / s8;
    for (int k = 0; k < K_TOP; ++k) {
      float w = ww[k] * inv;
      int e2 = sel[k];
      int pos = atomicAdd(&counts[e2], 1);
      tlist[e2 * T_TOK + pos] = t;
      wlist[e2 * T_TOK + pos] = w;
      topk_e[t * K_TOP + k] = e2;
      topk_p[t * K_TOP + k] = pos;
      topk_w[t * K_TOP + k] = w;
    }
  }
}

__global__ void scan_kernel(const int* __restrict__ counts, int* __restrict__ offsets)
{
  if (threadIdx.x == 0) {
    int run = 0;
    for (int e = 0; e < E_NUM; ++e) { offsets[e] = run; run += counts[e]; }
  }
}

// ---------------- Gate+Up: barrier-free per-wave MFMA streaming ----------------
// Each wave: 64 tokens x 32 F-cols, BOTH gate & up. K=2048, BK=32 (1 ks).
// A (bf16 xb) and B (fp32 wg/wu, converted in-reg) loaded directly from global
// with per-lane fragment addressing. No LDS, no __syncthreads.
__global__ __launch_bounds__(256, 2) void gateup_kernel(
    const unsigned short* __restrict__ xb, const float* __restrict__ wg,
    const float* __restrict__ wu, const int* __restrict__ counts,
    const int* __restrict__ offsets, const int* __restrict__ tlist,
    unsigned short* __restrict__ hbuf)
{
  const int e = blockIdx.y;
  const int cnt = counts[e];
  const int w = blockIdx.x * 4 + (threadIdx.x >> 6);
  const int tm = w & 15;       // token tile (64 rows)  -- fast: block's 4 waves share tf
  const int tf = w >> 4;       // F tile (32 cols), 0..23
  if (cnt == 0 || tm * 64 >= cnt) return;
  const int lane = threadIdx.x & 63;
  const int l15 = lane & 15, l4 = lane >> 4;

  const char* aB = (const char*)xb;
  const char* gB = (const char*)(wg + (size_t)e * F_DIM * D_DIM);
  const char* uB = (const char*)(wu + (size_t)e * F_DIM * D_DIM);

  unsigned aoff[4];
#pragma unroll
  for (int fm = 0; fm < 4; ++fm) {
    int rg = tm * 64 + fm * 16 + l15;
    if (rg > cnt - 1) rg = cnt - 1;
    int tok = tlist[e * T_TOK + rg];
    aoff[fm] = (unsigned)tok * (D_DIM * 2) + l4 * 16;
  }
  unsigned boff[2];
#pragma unroll
  for (int fn = 0; fn < 2; ++fn) {
    int col = tf * 32 + fn * 16 + l15;
    boff[fn] = (unsigned)col * (D_DIM * 4) + l4 * 32;
  }

  v4f zero = {0.f, 0.f, 0.f, 0.f};
  v4f accg[4][2], accu[4][2];
#pragma unroll
  for (int fm = 0; fm < 4; ++fm)
#pragma unroll
    for (int fn = 0; fn < 2; ++fn) { accg[fm][fn] = zero; accu[fm][fn] = zero; }

  v8bf aC[4], gC[2], uC[2];
#pragma unroll
  for (int fm = 0; fm < 4; ++fm)
    aC[fm] = __builtin_bit_cast(v8bf, *reinterpret_cast<const v8us*>(aB + aoff[fm]));
#pragma unroll
  for (int fn = 0; fn < 2; ++fn) {
    v4f g0 = *reinterpret_cast<const v4f*>(gB + boff[fn]);
    v4f g1 = *reinterpret_cast<const v4f*>(gB + boff[fn] + 16);
    v4f u0 = *reinterpret_cast<const v4f*>(uB + boff[fn]);
    v4f u1 = *reinterpret_cast<const v4f*>(uB + boff[fn] + 16);
    gC[fn] = cvt8(g0, g1);
    uC[fn] = cvt8(u0, u1);
  }

#pragma unroll 2
  for (int k = 1; k < D_DIM / 32; ++k) {
    // issue next-step loads (1-deep rotation)
    v8us aN[4];
    v4f gN[2][2], uN[2][2];
#pragma unroll
    for (int fm = 0; fm < 4; ++fm)
      aN[fm] = *reinterpret_cast<const v8us*>(aB + aoff[fm] + k * 64);
#pragma unroll
    for (int fn = 0; fn < 2; ++fn) {
      const char* gp = gB + boff[fn] + k * 128;
      const char* up = uB + boff[fn] + k * 128;
      gN[fn][0] = *reinterpret_cast<const v4f*>(gp);
      gN[fn][1] = *reinterpret_cast<const v4f*>(gp + 16);
      uN[fn][0] = *reinterpret_cast<const v4f*>(up);
      uN[fn][1] = *reinterpret_cast<const v4f*>(up + 16);
    }
    // compute current step
#pragma unroll
    for (int fm = 0; fm < 4; ++fm)
#pragma unroll
      for (int fn = 0; fn < 2; ++fn) {
        accg[fm][fn] = __builtin_amdgcn_mfma_f32_16x16x32_bf16(aC[fm], gC[fn], accg[fm][fn], 0, 0, 0);
        accu[fm][fn] = __builtin_amdgcn_mfma_f32_16x16x32_bf16(aC[fm], uC[fn], accu[fm][fn], 0, 0, 0);
      }
    // rotate
#pragma unroll
    for (int fm = 0; fm < 4; ++fm) aC[fm] = __builtin_bit_cast(v8bf, aN[fm]);
#pragma unroll
    for (int fn = 0; fn < 2; ++fn) {
      gC[fn] = cvt8(gN[fn][0], gN[fn][1]);
      uC[fn] = cvt8(uN[fn][0], uN[fn][1]);
    }
  }
#pragma unroll
  for (int fm = 0; fm < 4; ++fm)
#pragma unroll
    for (int fn = 0; fn < 2; ++fn) {
      accg[fm][fn] = __builtin_amdgcn_mfma_f32_16x16x32_bf16(aC[fm], gC[fn], accg[fm][fn], 0, 0, 0);
      accu[fm][fn] = __builtin_amdgcn_mfma_f32_16x16x32_bf16(aC[fm], uC[fn], accu[fm][fn], 0, 0, 0);
    }

  const int off_e = offsets[e];
#pragma unroll
  for (int fm = 0; fm < 4; ++fm)
#pragma unroll
    for (int fn = 0; fn < 2; ++fn)
#pragma unroll
      for (int i = 0; i < 4; ++i) {
        int rg = tm * 64 + fm * 16 + l4 * 4 + i;
        if (rg < cnt) {
          int col = tf * 32 + fn * 16 + l15;
          float g = accg[fm][fn][i];
          float uu = accu[fm][fn][i];
          float h = g * (1.f / (1.f + __expf(-g))) * uu;
          hbuf[(size_t)(off_e + rg) * F_DIM + col] = f2b(h);
        }
      }
}

// ---------------- Down: barrier-free per-wave MFMA streaming ----------------
// Each wave: 64 slots x 32 D-cols. K=768, BK=32.
template <int STAGE>
__global__ __launch_bounds__(256, 4) void down_kernel(
    const unsigned short* __restrict__ hbuf, const float* __restrict__ wd,
    const int* __restrict__ counts, const int* __restrict__ offsets,
    const int* __restrict__ tlist, const float* __restrict__ wlist,
    unsigned short* __restrict__ ybuf, float* __restrict__ out)
{
  const int e = blockIdx.y;
  const int cnt = counts[e];
  const int w = blockIdx.x * 4 + (threadIdx.x >> 6);
  const int tm = w & 15;       // slot tile (64 rows)
  const int td = w >> 4;       // D tile (32 cols), 0..63
  if (cnt == 0 || tm * 64 >= cnt) return;
  const int off_e = offsets[e];
  const int lane = threadIdx.x & 63;
  const int l15 = lane & 15, l4 = lane >> 4;

  const char* aB = (const char*)hbuf;
  const char* bB = (const char*)(wd + (size_t)e * D_DIM * F_DIM);

  unsigned aoff[4];
#pragma unroll
  for (int fm = 0; fm < 4; ++fm) {
    int rg = tm * 64 + fm * 16 + l15;
    if (rg > cnt - 1) rg = cnt - 1;
    aoff[fm] = (unsigned)(off_e + rg) * (F_DIM * 2) + l4 * 16;
  }
  unsigned boff[2];
#pragma unroll
  for (int fn = 0; fn < 2; ++fn) {
    int col = td * 32 + fn * 16 + l15;
    boff[fn] = (unsigned)col * (F_DIM * 4) + l4 * 32;
  }

  v4f zero = {0.f, 0.f, 0.f, 0.f};
  v4f acc[4][2];
#pragma unroll
  for (int fm = 0; fm < 4; ++fm)
#pragma unroll
    for (int fn = 0; fn < 2; ++fn) acc[fm][fn] = zero;

  v8bf aC[4], bC[2];
#pragma unroll
  for (int fm = 0; fm < 4; ++fm)
    aC[fm] = __builtin_bit_cast(v8bf, *reinterpret_cast<const v8us*>(aB + aoff[fm]));
#pragma unroll
  for (int fn = 0; fn < 2; ++fn) {
    v4f b0 = *reinterpret_cast<const v4f*>(bB + boff[fn]);
    v4f b1 = *reinterpret_cast<const v4f*>(bB + boff[fn] + 16);
    bC[fn] = cvt8(b0, b1);
  }

#pragma unroll 2
  for (int k = 1; k < F_DIM / 32; ++k) {
    v8us aN[4];
    v4f bN[2][2];
#pragma unroll
    for (int fm = 0; fm < 4; ++fm)
      aN[fm] = *reinterpret_cast<const v8us*>(aB + aoff[fm] + k * 64);
#pragma unroll
    for (int fn = 0; fn < 2; ++fn) {
      const char* bp = bB + boff[fn] + k * 128;
      bN[fn][0] = *reinterpret_cast<const v4f*>(bp);
      bN[fn][1] = *reinterpret_cast<const v4f*>(bp + 16);
    }
#pragma unroll
    for (int fm = 0; fm < 4; ++fm)
#pragma unroll
      for (int fn = 0; fn < 2; ++fn)
        acc[fm][fn] = __builtin_amdgcn_mfma_f32_16x16x32_bf16(aC[fm], bC[fn], acc[fm][fn], 0, 0, 0);
#pragma unroll
    for (int fm = 0; fm < 4; ++fm) aC[fm] = __builtin_bit_cast(v8bf, aN[fm]);
#pragma unroll
    for (int fn = 0; fn < 2; ++fn) bC[fn] = cvt8(bN[fn][0], bN[fn][1]);
  }
#pragma unroll
  for (int fm = 0; fm < 4; ++fm)
#pragma unroll
    for (int fn = 0; fn < 2; ++fn)
      acc[fm][fn] = __builtin_amdgcn_mfma_f32_16x16x32_bf16(aC[fm], bC[fn], acc[fm][fn], 0, 0, 0);

#pragma unroll
  for (int fm = 0; fm < 4; ++fm)
#pragma unroll
    for (int fn = 0; fn < 2; ++fn)
#pragma unroll
      for (int i = 0; i < 4; ++i) {
        int rg = tm * 64 + fm * 16 + l4 * 4 + i;
        if (rg < cnt) {
          int col = td * 32 + fn * 16 + l15;
          float y = acc[fm][fn][i];
          if (STAGE) {
            ybuf[(size_t)(off_e + rg) * D_DIM + col] = f2b(y);
          } else {
            int tok = tlist[e * T_TOK + rg];
            float ww = wlist[e * T_TOK + rg];
            atomicAdd(out + (size_t)tok * D_DIM + col, ww * y);
          }
        }
      }
}

// ---------------- Combine: out[t] = sum_k w_k * y[slot_k] ----------------
__global__ __launch_bounds__(256) void combine_kernel(
    const unsigned short* __restrict__ ybuf, const int* __restrict__ topk_e,
    const int* __restrict__ topk_p, const float* __restrict__ topk_w,
    const int* __restrict__ offsets, float* __restrict__ out)
{
  const int t = blockIdx.x, tid = threadIdx.x;
  const int d0 = tid * 8;
  float acc[8] = {0.f, 0.f, 0.f, 0.f, 0.f, 0.f, 0.f, 0.f};
#pragma unroll
  for (int k = 0; k < K_TOP; ++k) {
    int e = topk_e[t * K_TOP + k];
    int slot = offsets[e] + topk_p[t * K_TOP + k];
    float w = topk_w[t * K_TOP + k];
    v8us v = *reinterpret_cast<const v8us*>(ybuf + (size_t)slot * D_DIM + d0);
#pragma unroll
    for (int j = 0; j < 8; ++j) acc[j] += w * b2f(v[j]);
  }
  v4f o0 = {acc[0], acc[1], acc[2], acc[3]};
  v4f o1 = {acc[4], acc[5], acc[6], acc[7]};
  *reinterpret_cast<v4f*>(out + (size_t)t * D_DIM + d0) = o0;
  *reinterpret_cast<v4f*>(out + (size_t)t * D_DIM + d0 + 4) = o1;
}

extern "C" void kernel_launch(void* const* d_in, const int* in_sizes, int n_in,
                              void* d_out, int out_size, void* d_ws, size_t ws_size,
                              hipStream_t stream)
{
  const float* x  = (const float*)d_in[0];
  const float* gw = (const float*)d_in[1];
  const float* wg = (const float*)d_in[2];
  const float* wu = (const float*)d_in[3];
  const float* wd = (const float*)d_in[4];
  float* out = (float*)d_out;

  char* p = (char*)d_ws;
  auto alloc = [&](size_t bytes) {
    char* r = p;
    p += (bytes + 255) & ~(size_t)255;
    return r;
  };
  int* counts   = (int*)alloc(E_NUM * 4);
  int* offsets  = (int*)alloc(E_NUM * 4);
  int* tlist    = (int*)alloc((size_t)E_NUM * T_TOK * 4);
  float* wlist  = (float*)alloc((size_t)E_NUM * T_TOK * 4);
  int* topk_e   = (int*)alloc((size_t)T_TOK * K_TOP * 4);
  int* topk_p   = (int*)alloc((size_t)T_TOK * K_TOP * 4);
  float* topk_w = (float*)alloc((size_t)T_TOK * K_TOP * 4);
  unsigned short* xb   = (unsigned short*)alloc((size_t)T_TOK * D_DIM * 2);
  unsigned short* hbuf = (unsigned short*)alloc((size_t)T_TOK * K_TOP * F_DIM * 2);
  size_t need_atomic = (size_t)(p - (char*)d_ws);
  unsigned short* ybuf = (unsigned short*)alloc((size_t)T_TOK * K_TOP * D_DIM * 2);
  size_t need_stage = (size_t)(p - (char*)d_ws);

  if (ws_size < need_atomic) return;  // cannot run safely
  const bool stage = (ws_size >= need_stage);

  hipMemsetAsync(counts, 0, E_NUM * 4, stream);
  router_kernel<<<T_TOK, 256, 0, stream>>>(x, gw, xb, counts, tlist, topk_e, topk_p, topk_w, wlist);
  scan_kernel<<<1, 64, 0, stream>>>(counts, offsets);
  // gateup: waves = 24 tf x 16 tm per expert; 4 waves/block
  gateup_kernel<<<dim3(24 * 16 / 4, E_NUM), 256, 0, stream>>>(
      xb, wg, wu, counts, offsets, tlist, hbuf);
  if (stage) {
    // down: waves = 64 td x 16 tm per expert; 4 waves/block
    down_kernel<1><<<dim3(64 * 16 / 4, E_NUM), 256, 0, stream>>>(
        hbuf, wd, counts, offsets, tlist, wlist, ybuf, out);
    combine_kernel<<<T_TOK, 256, 0, stream>>>(ybuf, topk_e, topk_p, topk_w, offsets, out);
  } else {
    hipMemsetAsync(out, 0, (size_t)out_size * 4, stream);
    down_kernel<0><<<dim3(64 * 16 / 4, E_NUM), 256, 0, stream>>>(
        hbuf, wd, counts, offsets, tlist, wlist, ybuf, out);
  }
}

// Round 4
// 368.293 us; speedup vs baseline: 4.8723x; 4.8723x over previous
//
#include <hip/hip_runtime.h>

#define T_TOK 1024
#define D_DIM 2048
#define E_NUM 32
#define F_DIM 768
#define K_TOP 8

typedef __bf16 v8bf __attribute__((ext_vector_type(8)));
typedef float v4f __attribute__((ext_vector_type(4)));
typedef unsigned short v8us __attribute__((ext_vector_type(8)));

__device__ __forceinline__ unsigned short f2b(float f) {
  unsigned int u = __builtin_bit_cast(unsigned int, f);
  u += 0x7fffu + ((u >> 16) & 1u);   // RNE
  return (unsigned short)(u >> 16);
}
__device__ __forceinline__ float b2f(unsigned short s) {
  return __builtin_bit_cast(float, (unsigned int)s << 16);
}
__device__ __forceinline__ v8bf cvt8(v4f a, v4f b) {
  v8bf r;
  r[0] = (__bf16)a[0]; r[1] = (__bf16)a[1]; r[2] = (__bf16)a[2]; r[3] = (__bf16)a[3];
  r[4] = (__bf16)b[0]; r[5] = (__bf16)b[1]; r[6] = (__bf16)b[2]; r[7] = (__bf16)b[3];
  return r;
}
__device__ __forceinline__ void gload16(const void* g, void* l) {
  __builtin_amdgcn_global_load_lds(
      (const __attribute__((address_space(1))) void*)g,
      (__attribute__((address_space(3))) void*)l, 16, 0, 0);
}

// ---------------- Router: logits (fp32), top-8, bucket, x->bf16 ----------------
__global__ __launch_bounds__(256) void router_kernel(
    const float* __restrict__ x, const float* __restrict__ gw,
    unsigned short* __restrict__ xb, int* __restrict__ counts,
    int* __restrict__ tlist, int* __restrict__ topk_e, int* __restrict__ topk_p,
    float* __restrict__ topk_w, float* __restrict__ wlist)
{
  const int t = blockIdx.x, tid = threadIdx.x;
  const float* xr = x + (size_t)t * D_DIM;

  {
    v4f f0 = *reinterpret_cast<const v4f*>(xr + tid * 8);
    v4f f1 = *reinterpret_cast<const v4f*>(xr + tid * 8 + 4);
    v8us u;
    u[0] = f2b(f0[0]); u[1] = f2b(f0[1]); u[2] = f2b(f0[2]); u[3] = f2b(f0[3]);
    u[4] = f2b(f1[0]); u[5] = f2b(f1[1]); u[6] = f2b(f1[2]); u[7] = f2b(f1[3]);
    *reinterpret_cast<v8us*>(xb + (size_t)t * D_DIM + tid * 8) = u;
  }

  __shared__ float logits[E_NUM];
  const int lane = tid & 63, wave = tid >> 6;
  for (int j = 0; j < 8; ++j) {
    int e = wave * 8 + j;
    const float* wr = gw + (size_t)e * D_DIM;
    float s = 0.f;
#pragma unroll
    for (int i = 0; i < D_DIM / 64; ++i) s = fmaf(xr[lane + i * 64], wr[lane + i * 64], s);
#pragma unroll
    for (int off = 32; off > 0; off >>= 1) s += __shfl_xor(s, off);
    if (lane == 0) logits[e] = s;
  }
  __syncthreads();

  if (tid == 0) {
    float lg[E_NUM];
#pragma unroll
    for (int e2 = 0; e2 < E_NUM; ++e2) lg[e2] = logits[e2];
    int sel[K_TOP]; float sv[K_TOP];
    for (int k = 0; k < K_TOP; ++k) {
      int best = 0; float bv = -3.4e38f;
      for (int e2 = 0; e2 < E_NUM; ++e2)
        if (lg[e2] > bv) { bv = lg[e2]; best = e2; }
      sel[k] = best; sv[k] = bv; lg[best] = -3.4e38f;
    }
    float mx = sv[0], s8 = 0.f, ww[K_TOP];
    for (int k = 0; k < K_TOP; ++k) { ww[k] = __expf(sv[k] - mx); s8 += ww[k]; }
    float inv = 1.f / s8;
    for (int k = 0; k < K_TOP; ++k) {
      float w = ww[k] * inv;
      int e2 = sel[k];
      int pos = atomicAdd(&counts[e2], 1);
      tlist[e2 * T_TOK + pos] = t;
      wlist[e2 * T_TOK + pos] = w;
      topk_e[t * K_TOP + k] = e2;
      topk_p[t * K_TOP + k] = pos;
      topk_w[t * K_TOP + k] = w;
    }
  }
}

__global__ void scan_kernel(const int* __restrict__ counts, int* __restrict__ offsets)
{
  if (threadIdx.x == 0) {
    int run = 0;
    for (int e = 0; e < E_NUM; ++e) { offsets[e] = run; run += counts[e]; }
  }
}

// ---------------- Gate+Up grouped GEMM, 2-phase gload_lds pipeline ----------------
// 512 thr (8 waves, 4x2). BM=256, BN=64 (both g & u), BK=32, K=2048, NT=64.
// LDS 64KB: A dbuf 2x16KB @0; Bg dbuf 2x8KB @32768; Bu dbuf 2x8KB @49152.
// A staged bf16 (xb); B staged fp32 (wg/wu), converted bf16 at consume.
// Source-pre-swizzled, linear LDS dest (global_load_lds rule).
__global__ __launch_bounds__(512, 4) void gateup_kernel(
    const unsigned short* __restrict__ xb, const float* __restrict__ wg,
    const float* __restrict__ wu, const int* __restrict__ counts,
    const int* __restrict__ offsets, const int* __restrict__ tlist,
    unsigned short* __restrict__ hbuf)
{
  const int e = blockIdx.y;
  const int cnt = counts[e];
  const int tf = blockIdx.x % 12;
  const int tm = blockIdx.x / 12;
  if (tm * 256 >= cnt) return;

  __shared__ __align__(16) unsigned char lds[65536];

  const int tid = threadIdx.x;
  const int lane = tid & 63;
  const int wave = tid >> 6;
  const int wm = wave >> 1;  // 0..3 (64 rows)
  const int wn = wave & 1;   // 0..1 (32 cols)
  const int l15 = lane & 15;
  const int l4 = lane >> 4;

  // ---- staging descriptors (fixed per thread; only k0 advances) ----
  const char* xbB = (const char*)xb;
  unsigned asrc[2];
  unsigned aldsOff[2];
#pragma unroll
  for (int c = 0; c < 2; ++c) {
    int chunk = wave + c * 8;            // 0..15
    int row = chunk * 16 + (lane >> 2);  // 4 lanes per 64B row
    int rg = tm * 256 + row;
    if (rg > cnt - 1) rg = cnt - 1;
    int tok = tlist[e * T_TOK + rg];
    int g = ((lane & 3) - (row >> 1)) & 3;   // inverse of slot=(g+(row>>1))&3
    asrc[c] = (unsigned)tok * (D_DIM * 2) + (unsigned)(g * 16);
    aldsOff[c] = (unsigned)(chunk * 1024);
  }
  unsigned bsrcOff, bldsOff;
  {
    int row = wave * 8 + (lane >> 3);    // 8 lanes per 128B row
    int g = (lane & 7) ^ (row & 7);      // slot = g ^ (row&7)
    bsrcOff = (unsigned)((tf * 64 + row) * (D_DIM * 4) + g * 16);
    bldsOff = (unsigned)(wave * 1024);
  }
  const char* gB = (const char*)wg + (size_t)e * F_DIM * D_DIM * 4;
  const char* uB = (const char*)wu + (size_t)e * F_DIM * D_DIM * 4;

  // ---- ds_read addresses (buffer-relative) ----
  unsigned aRd[4];
#pragma unroll
  for (int fm = 0; fm < 4; ++fm) {
    int row = wm * 64 + fm * 16 + l15;
    aRd[fm] = (unsigned)(row * 64 + (((l4) + (row >> 1)) & 3) * 16);
  }
  unsigned bRd[2][2];
#pragma unroll
  for (int fn = 0; fn < 2; ++fn) {
    int row = wn * 32 + fn * 16 + l15;
    bRd[fn][0] = (unsigned)(row * 128 + (((2 * l4) ^ (row & 7)) * 16));
    bRd[fn][1] = (unsigned)(row * 128 + (((2 * l4 + 1) ^ (row & 7)) * 16));
  }

  v4f zero = {0.f, 0.f, 0.f, 0.f};
  v4f accg[4][2], accu[4][2];
#pragma unroll
  for (int fm = 0; fm < 4; ++fm)
#pragma unroll
    for (int fn = 0; fn < 2; ++fn) { accg[fm][fn] = zero; accu[fm][fn] = zero; }

  auto STAGE = [&](unsigned abufo, unsigned bbufo, int t) {
    unsigned ak = (unsigned)t * 64;    // 32 bf16
    unsigned bk = (unsigned)t * 128;   // 32 f32
    gload16(xbB + asrc[0] + ak, &lds[abufo + aldsOff[0]]);
    gload16(xbB + asrc[1] + ak, &lds[abufo + aldsOff[1]]);
    gload16(gB + bsrcOff + bk, &lds[32768u + bbufo + bldsOff]);
    gload16(uB + bsrcOff + bk, &lds[49152u + bbufo + bldsOff]);
  };
  auto COMPUTE = [&](unsigned ao, unsigned bo) {
    v8bf af[4], bg[2], bu[2];
#pragma unroll
    for (int fm = 0; fm < 4; ++fm)
      af[fm] = __builtin_bit_cast(v8bf, *reinterpret_cast<const v8us*>(&lds[ao + aRd[fm]]));
#pragma unroll
    for (int fn = 0; fn < 2; ++fn) {
      v4f g0 = *reinterpret_cast<const v4f*>(&lds[32768u + bo + bRd[fn][0]]);
      v4f g1 = *reinterpret_cast<const v4f*>(&lds[32768u + bo + bRd[fn][1]]);
      v4f u0 = *reinterpret_cast<const v4f*>(&lds[49152u + bo + bRd[fn][0]]);
      v4f u1 = *reinterpret_cast<const v4f*>(&lds[49152u + bo + bRd[fn][1]]);
      bg[fn] = cvt8(g0, g1);
      bu[fn] = cvt8(u0, u1);
    }
#pragma unroll
    for (int fm = 0; fm < 4; ++fm)
#pragma unroll
      for (int fn = 0; fn < 2; ++fn) {
        accg[fm][fn] = __builtin_amdgcn_mfma_f32_16x16x32_bf16(af[fm], bg[fn], accg[fm][fn], 0, 0, 0);
        accu[fm][fn] = __builtin_amdgcn_mfma_f32_16x16x32_bf16(af[fm], bu[fn], accu[fm][fn], 0, 0, 0);
      }
  };

  STAGE(0u, 0u, 0);
  __syncthreads();
#pragma unroll 2
  for (int t = 0; t < D_DIM / 32; ++t) {
    unsigned buf = (unsigned)(t & 1);
    if (t < D_DIM / 32 - 1) STAGE((buf ^ 1u) * 16384u, (buf ^ 1u) * 8192u, t + 1);
    COMPUTE(buf * 16384u, buf * 8192u);
    __syncthreads();
  }

  const int off_e = offsets[e];
#pragma unroll
  for (int fm = 0; fm < 4; ++fm)
#pragma unroll
    for (int fn = 0; fn < 2; ++fn)
#pragma unroll
      for (int i = 0; i < 4; ++i) {
        int rloc = wm * 64 + fm * 16 + l4 * 4 + i;
        int rg = tm * 256 + rloc;
        if (rg < cnt) {
          int col = tf * 64 + wn * 32 + fn * 16 + l15;
          float g = accg[fm][fn][i];
          float uu = accu[fm][fn][i];
          float h = g * (1.f / (1.f + __expf(-g))) * uu;
          hbuf[(size_t)(off_e + rg) * F_DIM + col] = f2b(h);
        }
      }
}

// ---------------- Down grouped GEMM, same 2-phase pipeline ----------------
// BM=256, BN=64, BK=32, K=768, NT=24. LDS 48KB: A dbuf 2x16KB @0; B dbuf 2x8KB @32768.
template <int STAGEOUT>
__global__ __launch_bounds__(512, 4) void down_kernel(
    const unsigned short* __restrict__ hbuf, const float* __restrict__ wd,
    const int* __restrict__ counts, const int* __restrict__ offsets,
    const int* __restrict__ tlist, const float* __restrict__ wlist,
    unsigned short* __restrict__ ybuf, float* __restrict__ out)
{
  const int e = blockIdx.y;
  const int cnt = counts[e];
  const int td = blockIdx.x % 32;
  const int tm = blockIdx.x / 32;
  if (tm * 256 >= cnt) return;
  const int off_e = offsets[e];

  __shared__ __align__(16) unsigned char lds[49152];

  const int tid = threadIdx.x;
  const int lane = tid & 63;
  const int wave = tid >> 6;
  const int wm = wave >> 1;
  const int wn = wave & 1;
  const int l15 = lane & 15;
  const int l4 = lane >> 4;

  const char* hB = (const char*)hbuf;
  unsigned asrc[2];
  unsigned aldsOff[2];
#pragma unroll
  for (int c = 0; c < 2; ++c) {
    int chunk = wave + c * 8;
    int row = chunk * 16 + (lane >> 2);
    int rg = tm * 256 + row;
    if (rg > cnt - 1) rg = cnt - 1;
    int g = ((lane & 3) - (row >> 1)) & 3;
    asrc[c] = (unsigned)(off_e + rg) * (F_DIM * 2) + (unsigned)(g * 16);
    aldsOff[c] = (unsigned)(chunk * 1024);
  }
  unsigned bsrcOff, bldsOff;
  {
    int row = wave * 8 + (lane >> 3);
    int g = (lane & 7) ^ (row & 7);
    bsrcOff = (unsigned)((td * 64 + row) * (F_DIM * 4) + g * 16);
    bldsOff = (unsigned)(wave * 1024);
  }
  const char* bB = (const char*)wd + (size_t)e * D_DIM * F_DIM * 4;

  unsigned aRd[4];
#pragma unroll
  for (int fm = 0; fm < 4; ++fm) {
    int row = wm * 64 + fm * 16 + l15;
    aRd[fm] = (unsigned)(row * 64 + (((l4) + (row >> 1)) & 3) * 16);
  }
  unsigned bRd[2][2];
#pragma unroll
  for (int fn = 0; fn < 2; ++fn) {
    int row = wn * 32 + fn * 16 + l15;
    bRd[fn][0] = (unsigned)(row * 128 + (((2 * l4) ^ (row & 7)) * 16));
    bRd[fn][1] = (unsigned)(row * 128 + (((2 * l4 + 1) ^ (row & 7)) * 16));
  }

  v4f zero = {0.f, 0.f, 0.f, 0.f};
  v4f acc[4][2];
#pragma unroll
  for (int fm = 0; fm < 4; ++fm)
#pragma unroll
    for (int fn = 0; fn < 2; ++fn) acc[fm][fn] = zero;

  auto STAGE = [&](unsigned abufo, unsigned bbufo, int t) {
    unsigned ak = (unsigned)t * 64;
    unsigned bk = (unsigned)t * 128;
    gload16(hB + asrc[0] + ak, &lds[abufo + aldsOff[0]]);
    gload16(hB + asrc[1] + ak, &lds[abufo + aldsOff[1]]);
    gload16(bB + bsrcOff + bk, &lds[32768u + bbufo + bldsOff]);
  };
  auto COMPUTE = [&](unsigned ao, unsigned bo) {
    v8bf af[4], bf_[2];
#pragma unroll
    for (int fm = 0; fm < 4; ++fm)
      af[fm] = __builtin_bit_cast(v8bf, *reinterpret_cast<const v8us*>(&lds[ao + aRd[fm]]));
#pragma unroll
    for (int fn = 0; fn < 2; ++fn) {
      v4f b0 = *reinterpret_cast<const v4f*>(&lds[32768u + bo + bRd[fn][0]]);
      v4f b1 = *reinterpret_cast<const v4f*>(&lds[32768u + bo + bRd[fn][1]]);
      bf_[fn] = cvt8(b0, b1);
    }
#pragma unroll
    for (int fm = 0; fm < 4; ++fm)
#pragma unroll
      for (int fn = 0; fn < 2; ++fn)
        acc[fm][fn] = __builtin_amdgcn_mfma_f32_16x16x32_bf16(af[fm], bf_[fn], acc[fm][fn], 0, 0, 0);
  };

  STAGE(0u, 0u, 0);
  __syncthreads();
#pragma unroll 2
  for (int t = 0; t < F_DIM / 32; ++t) {
    unsigned buf = (unsigned)(t & 1);
    if (t < F_DIM / 32 - 1) STAGE((buf ^ 1u) * 16384u, (buf ^ 1u) * 8192u, t + 1);
    COMPUTE(buf * 16384u, buf * 8192u);
    __syncthreads();
  }

#pragma unroll
  for (int fm = 0; fm < 4; ++fm)
#pragma unroll
    for (int fn = 0; fn < 2; ++fn)
#pragma unroll
      for (int i = 0; i < 4; ++i) {
        int rloc = wm * 64 + fm * 16 + l4 * 4 + i;
        int rg = tm * 256 + rloc;
        if (rg < cnt) {
          int col = td * 64 + wn * 32 + fn * 16 + l15;
          float y = acc[fm][fn][i];
          if (STAGEOUT) {
            ybuf[(size_t)(off_e + rg) * D_DIM + col] = f2b(y);
          } else {
            int tok = tlist[e * T_TOK + rg];
            float w = wlist[e * T_TOK + rg];
            atomicAdd(out + (size_t)tok * D_DIM + col, w * y);
          }
        }
      }
}

// ---------------- Combine: out[t] = sum_k w_k * y[slot_k] ----------------
__global__ __launch_bounds__(256) void combine_kernel(
    const unsigned short* __restrict__ ybuf, const int* __restrict__ topk_e,
    const int* __restrict__ topk_p, const float* __restrict__ topk_w,
    const int* __restrict__ offsets, float* __restrict__ out)
{
  const int t = blockIdx.x, tid = threadIdx.x;
  const int d0 = tid * 8;
  float acc[8] = {0.f, 0.f, 0.f, 0.f, 0.f, 0.f, 0.f, 0.f};
#pragma unroll
  for (int k = 0; k < K_TOP; ++k) {
    int e = topk_e[t * K_TOP + k];
    int slot = offsets[e] + topk_p[t * K_TOP + k];
    float w = topk_w[t * K_TOP + k];
    v8us v = *reinterpret_cast<const v8us*>(ybuf + (size_t)slot * D_DIM + d0);
#pragma unroll
    for (int j = 0; j < 8; ++j) acc[j] += w * b2f(v[j]);
  }
  v4f o0 = {acc[0], acc[1], acc[2], acc[3]};
  v4f o1 = {acc[4], acc[5], acc[6], acc[7]};
  *reinterpret_cast<v4f*>(out + (size_t)t * D_DIM + d0) = o0;
  *reinterpret_cast<v4f*>(out + (size_t)t * D_DIM + d0 + 4) = o1;
}

extern "C" void kernel_launch(void* const* d_in, const int* in_sizes, int n_in,
                              void* d_out, int out_size, void* d_ws, size_t ws_size,
                              hipStream_t stream)
{
  const float* x  = (const float*)d_in[0];
  const float* gw = (const float*)d_in[1];
  const float* wg = (const float*)d_in[2];
  const float* wu = (const float*)d_in[3];
  const float* wd = (const float*)d_in[4];
  float* out = (float*)d_out;

  char* p = (char*)d_ws;
  auto alloc = [&](size_t bytes) {
    char* r = p;
    p += (bytes + 255) & ~(size_t)255;
    return r;
  };
  int* counts   = (int*)alloc(E_NUM * 4);
  int* offsets  = (int*)alloc(E_NUM * 4);
  int* tlist    = (int*)alloc((size_t)E_NUM * T_TOK * 4);
  float* wlist  = (float*)alloc((size_t)E_NUM * T_TOK * 4);
  int* topk_e   = (int*)alloc((size_t)T_TOK * K_TOP * 4);
  int* topk_p   = (int*)alloc((size_t)T_TOK * K_TOP * 4);
  float* topk_w = (float*)alloc((size_t)T_TOK * K_TOP * 4);
  unsigned short* xb   = (unsigned short*)alloc((size_t)T_TOK * D_DIM * 2);
  unsigned short* hbuf = (unsigned short*)alloc((size_t)T_TOK * K_TOP * F_DIM * 2);
  size_t need_atomic = (size_t)(p - (char*)d_ws);
  unsigned short* ybuf = (unsigned short*)alloc((size_t)T_TOK * K_TOP * D_DIM * 2);
  size_t need_stage = (size_t)(p - (char*)d_ws);

  if (ws_size < need_atomic) return;
  const bool stage = (ws_size >= need_stage);

  hipMemsetAsync(counts, 0, E_NUM * 4, stream);
  router_kernel<<<T_TOK, 256, 0, stream>>>(x, gw, xb, counts, tlist, topk_e, topk_p, topk_w, wlist);
  scan_kernel<<<1, 64, 0, stream>>>(counts, offsets);
  gateup_kernel<<<dim3(12 * 4, E_NUM), 512, 0, stream>>>(
      xb, wg, wu, counts, offsets, tlist, hbuf);
  if (stage) {
    down_kernel<1><<<dim3(32 * 4, E_NUM), 512, 0, stream>>>(
        hbuf, wd, counts, offsets, tlist, wlist, ybuf, out);
    combine_kernel<<<T_TOK, 256, 0, stream>>>(ybuf, topk_e, topk_p, topk_w, offsets, out);
  } else {
    hipMemsetAsync(out, 0, (size_t)out_size * 4, stream);
    down_kernel<0><<<dim3(32 * 4, E_NUM), 512, 0, stream>>>(
        hbuf, wd, counts, offsets, tlist, wlist, ybuf, out);
  }
}